// Round 1
// baseline (1089.404 us; speedup 1.0000x reference)
//
#include <hip/hip_runtime.h>
#include <hip/hip_bf16.h>

#define KDIM 1024   // 2*ENC_H
#define HDIM 1024   // DEC_H
#define NB   32
#define NS   2048
#define BM   32

typedef __attribute__((ext_vector_type(8))) short bf16x8_t;
typedef __attribute__((ext_vector_type(4))) float f32x4_t;
typedef __attribute__((ext_vector_type(4))) unsigned int u32x4_t;
typedef __attribute__((ext_vector_type(2))) unsigned int u32x2_t;

__device__ __forceinline__ unsigned int pack2bf(float a, float b) {
    union { float f; unsigned int u; } ua, ub;
    ua.f = a; ub.f = b;
    unsigned int ra = (ua.u + 0x7fffu + ((ua.u >> 16) & 1u)) >> 16;  // RNE
    unsigned int rb = (ub.u + 0x7fffu + ((ub.u >> 16) & 1u)) >> 16;
    return ra | (rb << 16);
}

// ---- kernel 1a: W_e = attn_w[:, 1024:2048] -> bf16 [h][e] ----
__global__ void cvt_we_k(const float* __restrict__ attn_w, unsigned short* __restrict__ we) {
    const int h = blockIdx.x;      // 1024
    const int t = threadIdx.x;     // 256
    const f32x4_t v = *(const f32x4_t*)(attn_w + (size_t)h * 2048 + 1024 + (size_t)t * 4);
    u32x2_t o;
    o[0] = pack2bf(v[0], v[1]);
    o[1] = pack2bf(v[2], v[3]);
    *(u32x2_t*)(we + (size_t)h * 1024 + (size_t)t * 4) = o;
}

// ---- kernel 1b: proj_s[b][h] = sum_d s[b,d] * attn_w[h, d]  (fp32) ----
// one wave per h, loops b. grid 256 x 256 threads = 1024 waves.
__global__ void proj_s_k(const float* __restrict__ s, const float* __restrict__ attn_w,
                         float* __restrict__ ps) {
    const int h = (blockIdx.x * blockDim.x + threadIdx.x) >> 6;  // 0..1023
    const int lane = threadIdx.x & 63;
    const float* wr = attn_w + (size_t)h * 2048;
    float w[16];
#pragma unroll
    for (int i = 0; i < 16; ++i) w[i] = wr[lane + 64 * i];
    for (int b = 0; b < 32; ++b) {
        const float* sr = s + (size_t)b * 1024;
        float a = 0.f;
#pragma unroll
        for (int i = 0; i < 16; ++i) a = fmaf(w[i], sr[lane + 64 * i], a);
#pragma unroll
        for (int off = 32; off >= 1; off >>= 1) a += __shfl_xor(a, off, 64);
        if (lane == 0) ps[b * 1024 + h] = a;
    }
}

// ---- kernel 2: fused  pe-GEMM + tanh + v-dot -> scores[65536] ----
// grid 2048 blocks (BM=32 rows each), 512 threads = 8 waves = 2 m-tiles x 4 n-strips.
// A (enc rows, bf16) staged in 64 KB LDS with chunk-XOR swizzle; full N looped in 4 iters.
__launch_bounds__(512, 4)
__global__ void fused_main_k(const float* __restrict__ enc,
                             const unsigned short* __restrict__ we,
                             const float* __restrict__ ps,
                             const float* __restrict__ vw,
                             float* __restrict__ scores) {
    __shared__ unsigned short lds_a[BM * 1024];  // 64 KB, swizzled 16B chunks

    const int t = threadIdx.x;
    const int m_base = blockIdx.x * BM;
    const int bidx = m_base >> 11;  // batch = row/2048

    // ---- stage A: 32 rows x 1024 f32 -> bf16 LDS ----
    {
        const float* abase = enc + (size_t)m_base * KDIM;
#pragma unroll
        for (int i = 0; i < 8; ++i) {
            const int g = i * 512 + t;   // 8-element group id, 0..4095
            const int r = g >> 7;        // row 0..31
            const int c = g & 127;       // 16B chunk within row
            const f32x4_t f0 = __builtin_nontemporal_load((const f32x4_t*)(abase + (size_t)g * 8));
            const f32x4_t f1 = __builtin_nontemporal_load((const f32x4_t*)(abase + (size_t)g * 8 + 4));
            u32x4_t p;
            p[0] = pack2bf(f0[0], f0[1]);
            p[1] = pack2bf(f0[2], f0[3]);
            p[2] = pack2bf(f1[0], f1[1]);
            p[3] = pack2bf(f1[2], f1[3]);
            *(u32x4_t*)&lds_a[r * 1024 + ((c ^ (r & 7)) << 3)] = p;
        }
    }
    __syncthreads();

    const int lane = t & 63;
    const int wid  = t >> 6;    // 0..7
    const int mi   = wid & 1;   // m-tile
    const int nsw  = wid >> 1;  // n-strip 0..3
    const int l15  = lane & 15;
    const int l4   = lane >> 4;         // 0..3
    const int ar   = mi * 16 + l15;     // A row 0..31
    const int arx  = ar & 7;

    float sc4[4] = {0.f, 0.f, 0.f, 0.f};

    const unsigned short* bp0 = we + (size_t)l15 * 1024 + l4 * 8;

    for (int ni = 0; ni < 4; ++ni) {
        const int hb = ni * 256 + nsw * 64;  // strip base in h
        const unsigned short* bp = bp0 + (size_t)hb * 1024;
        f32x4_t acc[4];
#pragma unroll
        for (int nf = 0; nf < 4; ++nf) { acc[nf][0] = 0.f; acc[nf][1] = 0.f; acc[nf][2] = 0.f; acc[nf][3] = 0.f; }

#pragma unroll
        for (int ks = 0; ks < 32; ++ks) {
            bf16x8_t bfr[4];
#pragma unroll
            for (int nf = 0; nf < 4; ++nf)
                bfr[nf] = *(const bf16x8_t*)(bp + nf * 16384 + ks * 32);
            const int sw = (ks * 4 + l4) ^ arx;
            const bf16x8_t afr = *(const bf16x8_t*)&lds_a[ar * 1024 + (sw << 3)];
#pragma unroll
            for (int nf = 0; nf < 4; ++nf)
                acc[nf] = __builtin_amdgcn_mfma_f32_16x16x32_bf16(afr, bfr[nf], acc[nf], 0, 0, 0);
        }

        // epilogue: tanh(ps + pe) * v, accumulate per-lane (4 C-rows per lane)
#pragma unroll
        for (int nf = 0; nf < 4; ++nf) {
            const int h = hb + nf * 16 + l15;
            const float pv = ps[bidx * 1024 + h];
            const float vv = vw[h];
#pragma unroll
            for (int j = 0; j < 4; ++j) {
                const float x = acc[nf][j] + pv;
                const float e = __expf(2.0f * x);
                const float th = 1.0f - __fdividef(2.0f, e + 1.0f);
                sc4[j] = fmaf(vv, th, sc4[j]);
            }
        }
    }

    // reduce across the 16 lanes of each column group (masks < 16 keep l4 fixed)
#pragma unroll
    for (int off = 1; off < 16; off <<= 1) {
#pragma unroll
        for (int j = 0; j < 4; ++j) sc4[j] += __shfl_xor(sc4[j], off, 64);
    }

    __syncthreads();  // all A reads done; reuse LDS
    float* slds = (float*)lds_a;  // [32 rows][4 strips]
    if (l15 == 0) {
#pragma unroll
        for (int j = 0; j < 4; ++j)
            slds[(mi * 16 + l4 * 4 + j) * 4 + nsw] = sc4[j];
    }
    __syncthreads();
    if (t < 32) {
        scores[m_base + t] = slds[t * 4] + slds[t * 4 + 1] + slds[t * 4 + 2] + slds[t * 4 + 3];
    }
}

// ---- kernel 3: row softmax over S=2048 per batch ----
__global__ void softmax_k(const float* __restrict__ sc, float* __restrict__ out) {
    const int b = blockIdx.x;   // 32
    const int t = threadIdx.x;  // 256
    const int lane = t & 63;
    const int w = t >> 6;
    const float* row = sc + (size_t)b * 2048;
    float x[8];
#pragma unroll
    for (int i = 0; i < 8; ++i) x[i] = row[i * 256 + t];
    float m = x[0];
#pragma unroll
    for (int i = 1; i < 8; ++i) m = fmaxf(m, x[i]);
#pragma unroll
    for (int off = 32; off >= 1; off >>= 1) m = fmaxf(m, __shfl_xor(m, off, 64));
    __shared__ float sred[4];
    __shared__ float sred2[4];
    if (lane == 0) sred[w] = m;
    __syncthreads();
    m = fmaxf(fmaxf(sred[0], sred[1]), fmaxf(sred[2], sred[3]));
    float ssum = 0.f;
#pragma unroll
    for (int i = 0; i < 8; ++i) { x[i] = expf(x[i] - m); ssum += x[i]; }
#pragma unroll
    for (int off = 32; off >= 1; off >>= 1) ssum += __shfl_xor(ssum, off, 64);
    if (lane == 0) sred2[w] = ssum;
    __syncthreads();
    const float inv = 1.0f / (sred2[0] + sred2[1] + sred2[2] + sred2[3]);
#pragma unroll
    for (int i = 0; i < 8; ++i) out[(size_t)b * 2048 + i * 256 + t] = x[i] * inv;
}

extern "C" void kernel_launch(void* const* d_in, const int* in_sizes, int n_in,
                              void* d_out, int out_size, void* d_ws, size_t ws_size,
                              hipStream_t stream) {
    const float* s      = (const float*)d_in[0];
    const float* enc    = (const float*)d_in[1];
    const float* attn_w = (const float*)d_in[2];
    const float* vw     = (const float*)d_in[3];
    float* out = (float*)d_out;

    unsigned short* we = (unsigned short*)d_ws;                             // 2 MB bf16 W_e
    float* ps     = (float*)((char*)d_ws + (2u << 20));                     // 128 KB proj_s
    float* scores = (float*)((char*)d_ws + (2u << 20) + (128u << 10));      // 256 KB scores

    cvt_we_k<<<1024, 256, 0, stream>>>(attn_w, we);
    proj_s_k<<<256, 256, 0, stream>>>(s, attn_w, ps);
    fused_main_k<<<2048, 512, 0, stream>>>(enc, we, ps, vw, scores);
    softmax_k<<<32, 256, 0, stream>>>(scores, out);
}

// Round 2
// 235.690 us; speedup vs baseline: 4.6222x; 4.6222x over previous
//
#include <hip/hip_runtime.h>
#include <hip/hip_bf16.h>

#define KDIM 1024   // 2*ENC_H
#define HDIM 1024   // DEC_H
#define BM   64

typedef __attribute__((ext_vector_type(8))) short bf16x8_t;
typedef __attribute__((ext_vector_type(16))) float f32x16_t;
typedef __attribute__((ext_vector_type(4))) float f32x4_t;
typedef __attribute__((ext_vector_type(4))) unsigned int u32x4_t;
typedef __attribute__((ext_vector_type(2))) unsigned int u32x2_t;

__device__ __forceinline__ unsigned int pack2bf(float a, float b) {
    union { float f; unsigned int u; } ua, ub;
    ua.f = a; ub.f = b;
    unsigned int ra = (ua.u + 0x7fffu + ((ua.u >> 16) & 1u)) >> 16;  // RNE
    unsigned int rb = (ub.u + 0x7fffu + ((ub.u >> 16) & 1u)) >> 16;
    return ra | (rb << 16);
}

// ---- kernel 1a: W_e -> bf16, fragment-order layout we_t[ks][h][h5][8] ----
// element (h, e) -> we_t[(e>>4)*16384 + h*16 + (e&15)]
__global__ void cvt_we_k(const float* __restrict__ attn_w, unsigned short* __restrict__ we_t) {
    const int h = blockIdx.x;      // 1024
    const int t = threadIdx.x;     // 256 (handles e = 4t..4t+3)
    const f32x4_t v = *(const f32x4_t*)(attn_w + (size_t)h * 2048 + 1024 + (size_t)t * 4);
    u32x2_t o;
    o[0] = pack2bf(v[0], v[1]);
    o[1] = pack2bf(v[2], v[3]);
    const int ks  = t >> 2;         // e/16
    const int e15 = (t & 3) * 4;    // e&15
    *(u32x2_t*)&we_t[(size_t)ks * 16384 + h * 16 + e15] = o;
}

// ---- kernel 1b: proj_s[b][h] = sum_d s[b,d] * attn_w[h, d]  (fp32) ----
__global__ void proj_s_k(const float* __restrict__ s, const float* __restrict__ attn_w,
                         float* __restrict__ ps) {
    const int h = (blockIdx.x * blockDim.x + threadIdx.x) >> 6;  // 0..1023
    const int lane = threadIdx.x & 63;
    const float* wr = attn_w + (size_t)h * 2048;
    float w[16];
#pragma unroll
    for (int i = 0; i < 16; ++i) w[i] = wr[lane + 64 * i];
    for (int b = 0; b < 32; ++b) {
        const float* sr = s + (size_t)b * 1024;
        float a = 0.f;
#pragma unroll
        for (int i = 0; i < 16; ++i) a = fmaf(w[i], sr[lane + 64 * i], a);
#pragma unroll
        for (int off = 32; off >= 1; off >>= 1) a += __shfl_xor(a, off, 64);
        if (lane == 0) ps[b * 1024 + h] = a;
    }
}

// ---- kernel 2: fused pe-GEMM(32x32x16 MFMA) + tanh + v-dot -> scores ----
// 1024 blocks x 64 rows; 512 thr = 8 waves, wave w owns h-strip [w*128,(w+1)*128).
// A: 4-slot LDS ring of [64 rows][128 k] bf16 (64 KB), K-pipelined depth 2.
// B: we_t fragment-order global loads (L2-resident), reused for 2 m-frags.
__launch_bounds__(512, 2)
__global__ void fused_main_k(const float* __restrict__ enc,
                             const unsigned short* __restrict__ we_t,
                             const float* __restrict__ ps,
                             const float* __restrict__ vw,
                             float* __restrict__ scores) {
    __shared__ unsigned short lds_a[4 * 64 * 128];  // 64 KB ring

    const int t = threadIdx.x;
    const int m_base = blockIdx.x * BM;
    const int bidx = blockIdx.x >> 5;   // 32 blocks per batch row-group

    const int lane = t & 63;
    const int wid  = t >> 6;        // 0..7
    const int l31  = lane & 31;
    const int h5   = lane >> 5;     // 0..1
    const int hb   = wid * 128;

    // staging geometry: thread covers (row = i*32 + t>>4, 8 f32 at c8 = t&15)
    const int srow = t >> 4;        // 0..31
    const int sc8  = t & 15;

    auto stage_load = [&](int kc, f32x4_t* r) {
#pragma unroll
        for (int i = 0; i < 2; ++i) {
            const int row = i * 32 + srow;
            const float* p = enc + (size_t)(m_base + row) * KDIM + kc * 128 + sc8 * 8;
            r[2 * i]     = __builtin_nontemporal_load((const f32x4_t*)p);
            r[2 * i + 1] = __builtin_nontemporal_load((const f32x4_t*)(p + 4));
        }
    };
    auto stage_write = [&](int kc, const f32x4_t* r) {
        const int slot = kc & 3;
#pragma unroll
        for (int i = 0; i < 2; ++i) {
            const int row = i * 32 + srow;
            u32x4_t p;
            p[0] = pack2bf(r[2 * i][0], r[2 * i][1]);
            p[1] = pack2bf(r[2 * i][2], r[2 * i][3]);
            p[2] = pack2bf(r[2 * i + 1][0], r[2 * i + 1][1]);
            p[3] = pack2bf(r[2 * i + 1][2], r[2 * i + 1][3]);
            *(u32x4_t*)&lds_a[slot * 8192 + row * 128 + ((sc8 ^ (row & 7)) << 3)] = p;
        }
    };

    // B base: fragment-order; frag(nf, ks) at btile + ks*16384 + nf*512 (elems)
    const unsigned short* btile = we_t + (size_t)(hb + l31) * 16 + h5 * 8;

    f32x16_t acc[2][4];
#pragma unroll
    for (int m = 0; m < 2; ++m)
#pragma unroll
        for (int nf = 0; nf < 4; ++nf)
#pragma unroll
            for (int r = 0; r < 16; ++r) acc[m][nf][r] = 0.f;

    // prologue: stage chunks 0,1
    {
        f32x4_t r0[4], r1[4];
        stage_load(0, r0);
        stage_load(1, r1);
        stage_write(0, r0);
        stage_write(1, r1);
    }
    __syncthreads();

    const int xr = h5 ^ (l31 & 7);          // A-read swizzle precompute
    const int a0base = l31 * 128;           // lds row offsets (shorts)
    const int a1base = (32 + l31) * 128;

    for (int kc = 0; kc < 8; ++kc) {
        f32x4_t rs[4];
        if (kc < 6) stage_load(kc + 2, rs);   // issue early: latency hides under MFMA

        const unsigned short* slotp = lds_a + (kc & 3) * 8192;
        const unsigned short* bk = btile + (size_t)(kc * 8) * 16384;
#pragma unroll
        for (int ksl = 0; ksl < 8; ++ksl) {
            const int coff = ((ksl * 2) ^ xr) << 3;   // swizzled chunk offset (shorts)
            const bf16x8_t a0 = *(const bf16x8_t*)&slotp[a0base + coff];
            const bf16x8_t a1 = *(const bf16x8_t*)&slotp[a1base + coff];
            const unsigned short* bp = bk + (size_t)ksl * 16384;
            bf16x8_t bfr[4];
#pragma unroll
            for (int nf = 0; nf < 4; ++nf)
                bfr[nf] = *(const bf16x8_t*)(bp + nf * 512);
#pragma unroll
            for (int nf = 0; nf < 4; ++nf) {
                acc[0][nf] = __builtin_amdgcn_mfma_f32_32x32x16_bf16(a0, bfr[nf], acc[0][nf], 0, 0, 0);
                acc[1][nf] = __builtin_amdgcn_mfma_f32_32x32x16_bf16(a1, bfr[nf], acc[1][nf], 0, 0, 0);
            }
        }
        if (kc < 6) stage_write(kc + 2, rs);
        __syncthreads();
    }

    // ---- epilogue: tanh(ps + pe) * v, per-lane partials over C-rows ----
    float sc2[2][16];
#pragma unroll
    for (int m = 0; m < 2; ++m)
#pragma unroll
        for (int r = 0; r < 16; ++r) sc2[m][r] = 0.f;

#pragma unroll
    for (int nf = 0; nf < 4; ++nf) {
        const int h = hb + nf * 32 + l31;
        const float pv = ps[bidx * 1024 + h];
        const float vv = vw[h];
#pragma unroll
        for (int m = 0; m < 2; ++m)
#pragma unroll
            for (int r = 0; r < 16; ++r) {
                const float x = acc[m][nf][r] + pv;
                const float e = __expf(2.0f * x);
                const float th = 1.0f - __fdividef(2.0f, e + 1.0f);
                sc2[m][r] = fmaf(vv, th, sc2[m][r]);
            }
    }

    // reduce over the 32-lane column group (offsets < 32 keep h5 fixed)
#pragma unroll
    for (int off = 1; off < 32; off <<= 1)
#pragma unroll
        for (int m = 0; m < 2; ++m)
#pragma unroll
            for (int r = 0; r < 16; ++r)
                sc2[m][r] += __shfl_xor(sc2[m][r], off, 64);

    __syncthreads();   // all LDS A-reads done; reuse as partials buffer
    float* slds = (float*)lds_a;   // [8 waves][64 rows]
    if (l31 == 0) {
#pragma unroll
        for (int m = 0; m < 2; ++m)
#pragma unroll
            for (int r = 0; r < 16; ++r) {
                const int row = m * 32 + (r & 3) + 8 * (r >> 2) + 4 * h5;
                slds[wid * 64 + row] = sc2[m][r];
            }
    }
    __syncthreads();
    if (t < 64) {
        float v = 0.f;
#pragma unroll
        for (int w = 0; w < 8; ++w) v += slds[w * 64 + t];
        scores[m_base + t] = v;
    }
}

// ---- kernel 3: row softmax over S=2048 per batch ----
__global__ void softmax_k(const float* __restrict__ sc, float* __restrict__ out) {
    const int b = blockIdx.x;   // 32
    const int t = threadIdx.x;  // 256
    const int lane = t & 63;
    const int w = t >> 6;
    const float* row = sc + (size_t)b * 2048;
    float x[8];
#pragma unroll
    for (int i = 0; i < 8; ++i) x[i] = row[i * 256 + t];
    float m = x[0];
#pragma unroll
    for (int i = 1; i < 8; ++i) m = fmaxf(m, x[i]);
#pragma unroll
    for (int off = 32; off >= 1; off >>= 1) m = fmaxf(m, __shfl_xor(m, off, 64));
    __shared__ float sred[4];
    __shared__ float sred2[4];
    if (lane == 0) sred[w] = m;
    __syncthreads();
    m = fmaxf(fmaxf(sred[0], sred[1]), fmaxf(sred[2], sred[3]));
    float ssum = 0.f;
#pragma unroll
    for (int i = 0; i < 8; ++i) { x[i] = expf(x[i] - m); ssum += x[i]; }
#pragma unroll
    for (int off = 32; off >= 1; off >>= 1) ssum += __shfl_xor(ssum, off, 64);
    if (lane == 0) sred2[w] = ssum;
    __syncthreads();
    const float inv = 1.0f / (sred2[0] + sred2[1] + sred2[2] + sred2[3]);
#pragma unroll
    for (int i = 0; i < 8; ++i) out[(size_t)b * 2048 + i * 256 + t] = x[i] * inv;
}

extern "C" void kernel_launch(void* const* d_in, const int* in_sizes, int n_in,
                              void* d_out, int out_size, void* d_ws, size_t ws_size,
                              hipStream_t stream) {
    const float* s      = (const float*)d_in[0];
    const float* enc    = (const float*)d_in[1];
    const float* attn_w = (const float*)d_in[2];
    const float* vw     = (const float*)d_in[3];
    float* out = (float*)d_out;

    unsigned short* we = (unsigned short*)d_ws;                             // 2 MB bf16 we_t
    float* ps     = (float*)((char*)d_ws + (2u << 20));                     // 128 KB proj_s
    float* scores = (float*)((char*)d_ws + (2u << 20) + (128u << 10));      // 256 KB scores

    cvt_we_k<<<1024, 256, 0, stream>>>(attn_w, we);
    proj_s_k<<<256, 256, 0, stream>>>(s, attn_w, ps);
    fused_main_k<<<1024, 512, 0, stream>>>(enc, we, ps, vw, scores);
    softmax_k<<<32, 256, 0, stream>>>(scores, out);
}

// Round 3
// 223.509 us; speedup vs baseline: 4.8741x; 1.0545x over previous
//
#include <hip/hip_runtime.h>
#include <hip/hip_bf16.h>

#define KDIM 1024   // 2*ENC_H
#define HDIM 1024   // DEC_H
#define BM   64

typedef __attribute__((ext_vector_type(8))) short bf16x8_t;
typedef __attribute__((ext_vector_type(16))) float f32x16_t;
typedef __attribute__((ext_vector_type(4))) float f32x4_t;
typedef __attribute__((ext_vector_type(4))) unsigned int u32x4_t;
typedef __attribute__((ext_vector_type(2))) unsigned int u32x2_t;

__device__ __forceinline__ unsigned int pack2bf(float a, float b) {
    union { float f; unsigned int u; } ua, ub;
    ua.f = a; ub.f = b;
    unsigned int ra = (ua.u + 0x7fffu + ((ua.u >> 16) & 1u)) >> 16;  // RNE
    unsigned int rb = (ub.u + 0x7fffu + ((ub.u >> 16) & 1u)) >> 16;
    return ra | (rb << 16);
}

// ---- kernel 1a: W_e -> bf16, fragment-order layout we_t[ks][h][16] ----
// element (h, e) -> we_t[(e>>4)*16384 + h*16 + (e&15)]
__global__ void cvt_we_k(const float* __restrict__ attn_w, unsigned short* __restrict__ we_t) {
    const int h = blockIdx.x;      // 1024
    const int t = threadIdx.x;     // 256 (handles e = 4t..4t+3)
    const f32x4_t v = *(const f32x4_t*)(attn_w + (size_t)h * 2048 + 1024 + (size_t)t * 4);
    u32x2_t o;
    o[0] = pack2bf(v[0], v[1]);
    o[1] = pack2bf(v[2], v[3]);
    const int ks  = t >> 2;         // e/16
    const int e15 = (t & 3) * 4;    // e&15
    *(u32x2_t*)&we_t[(size_t)ks * 16384 + h * 16 + e15] = o;
}

// ---- kernel 1b: proj_s[b][h] = sum_d s[b,d] * attn_w[h, d]  (fp32) ----
__global__ void proj_s_k(const float* __restrict__ s, const float* __restrict__ attn_w,
                         float* __restrict__ ps) {
    const int h = (blockIdx.x * blockDim.x + threadIdx.x) >> 6;  // 0..1023
    const int lane = threadIdx.x & 63;
    const float* wr = attn_w + (size_t)h * 2048;
    float w[16];
#pragma unroll
    for (int i = 0; i < 16; ++i) w[i] = wr[lane + 64 * i];
    for (int b = 0; b < 32; ++b) {
        const float* sr = s + (size_t)b * 1024;
        float a = 0.f;
#pragma unroll
        for (int i = 0; i < 16; ++i) a = fmaf(w[i], sr[lane + 64 * i], a);
#pragma unroll
        for (int off = 32; off >= 1; off >>= 1) a += __shfl_xor(a, off, 64);
        if (lane == 0) ps[b * 1024 + h] = a;
    }
}

// ---- kernel 2: fused pe-GEMM(32x32x16 MFMA) + tanh + v-dot -> scores ----
// 1024 blocks x 64 rows; 512 thr = 8 waves, wave w owns h-strip [w*128,(w+1)*128).
// Single unrolled g-loop (8 kc x 8 ksl), 4 rotating B-frag buffers (issue at g,
// consume at g+3) to ride out L2/L3 latency. A: 4-slot LDS ring, stage at ksl=3.
__launch_bounds__(512, 2)
__global__ void fused_main_k(const float* __restrict__ enc,
                             const unsigned short* __restrict__ we_t,
                             const float* __restrict__ ps,
                             const float* __restrict__ vw,
                             float* __restrict__ scores) {
    __shared__ unsigned short lds_a[4 * 64 * 128];  // 64 KB ring

    const int t = threadIdx.x;
    // bijective XCD swizzle: 1024 blocks = 8 XCDs x 128 contiguous
    const int bid = blockIdx.x;
    const int swz = (bid & 7) * 128 + (bid >> 3);
    const int m_base = swz * BM;
    const int bidx = swz >> 5;          // batch index (32 blocks per batch)

    const int lane = t & 63;
    const int wid  = t >> 6;        // 0..7
    const int l31  = lane & 31;
    const int h5   = lane >> 5;     // 0..1
    const int hb   = wid * 128;

    // staging geometry: thread covers (row = i*32 + t>>4, 8 f32 at c8 = t&15)
    const int srow = t >> 4;        // 0..31
    const int sc8  = t & 15;

    auto stage_load = [&](int kc, f32x4_t* r) {
#pragma unroll
        for (int i = 0; i < 2; ++i) {
            const int row = i * 32 + srow;
            const float* p = enc + (size_t)(m_base + row) * KDIM + kc * 128 + sc8 * 8;
            r[2 * i]     = __builtin_nontemporal_load((const f32x4_t*)p);
            r[2 * i + 1] = __builtin_nontemporal_load((const f32x4_t*)(p + 4));
        }
    };
    auto stage_write = [&](int kc, const f32x4_t* r) {
        const int slot = kc & 3;
#pragma unroll
        for (int i = 0; i < 2; ++i) {
            const int row = i * 32 + srow;
            u32x4_t p;
            p[0] = pack2bf(r[2 * i][0], r[2 * i][1]);
            p[1] = pack2bf(r[2 * i][2], r[2 * i][3]);
            p[2] = pack2bf(r[2 * i + 1][0], r[2 * i + 1][1]);
            p[3] = pack2bf(r[2 * i + 1][2], r[2 * i + 1][3]);
            *(u32x4_t*)&lds_a[slot * 8192 + row * 128 + ((sc8 ^ (row & 7)) << 3)] = p;
        }
    };

    // B base: fragment-order; frag(g, nf) at btile + g*16384 + nf*512 (shorts)
    const unsigned short* btile = we_t + (size_t)(hb + l31) * 16 + h5 * 8;
    auto loadB = [&](int g, bf16x8_t* dst) {
        const unsigned short* bp = btile + (size_t)g * 16384;
        dst[0] = *(const bf16x8_t*)(bp);
        dst[1] = *(const bf16x8_t*)(bp + 512);
        dst[2] = *(const bf16x8_t*)(bp + 1024);
        dst[3] = *(const bf16x8_t*)(bp + 1536);
    };

    f32x16_t acc[2][4];
#pragma unroll
    for (int m = 0; m < 2; ++m)
#pragma unroll
        for (int nf = 0; nf < 4; ++nf)
#pragma unroll
            for (int r = 0; r < 16; ++r) acc[m][nf][r] = 0.f;

    bf16x8_t bbuf[4][4];

    // prologue: issue B prefetch for g=0..2 first (deepest latency), then stage A kc 0,1
    loadB(0, bbuf[0]);
    loadB(1, bbuf[1]);
    loadB(2, bbuf[2]);
    {
        f32x4_t r0[4], r1[4];
        stage_load(0, r0);
        stage_load(1, r1);
        stage_write(0, r0);
        stage_write(1, r1);
    }
    __syncthreads();

    const int xr = h5 ^ (l31 & 7);          // A-read swizzle precompute
    const int a0base = l31 * 128;           // lds row offsets (shorts)
    const int a1base = (32 + l31) * 128;

    f32x4_t rs[4];
#pragma unroll
    for (int g = 0; g < 64; ++g) {
        const int kc  = g >> 3;
        const int ksl = g & 7;

        if (g + 3 < 64) loadB(g + 3, bbuf[(g + 3) & 3]);       // depth-3 B prefetch
        if (ksl == 3 && kc < 6) stage_load(kc + 2, rs);        // A global->reg, early

        const unsigned short* slotp = lds_a + (kc & 3) * 8192;
        const int coff = ((ksl * 2) ^ xr) << 3;                // swizzled chunk offset
        const bf16x8_t a0 = *(const bf16x8_t*)&slotp[a0base + coff];
        const bf16x8_t a1 = *(const bf16x8_t*)&slotp[a1base + coff];
        const bf16x8_t* bfr = bbuf[g & 3];
#pragma unroll
        for (int nf = 0; nf < 4; ++nf) {
            acc[0][nf] = __builtin_amdgcn_mfma_f32_32x32x16_bf16(a0, bfr[nf], acc[0][nf], 0, 0, 0);
            acc[1][nf] = __builtin_amdgcn_mfma_f32_32x32x16_bf16(a1, bfr[nf], acc[1][nf], 0, 0, 0);
        }
        if (ksl == 7) {
            if (kc < 6) stage_write(kc + 2, rs);               // reg->LDS (waits rs)
            __syncthreads();
        }
    }

    // ---- epilogue: tanh(ps + pe) * v, per-lane partials over C-rows ----
    float sc2[2][16];
#pragma unroll
    for (int m = 0; m < 2; ++m)
#pragma unroll
        for (int r = 0; r < 16; ++r) sc2[m][r] = 0.f;

#pragma unroll
    for (int nf = 0; nf < 4; ++nf) {
        const int h = hb + nf * 32 + l31;
        const float pv = ps[bidx * 1024 + h];
        const float vv = vw[h];
#pragma unroll
        for (int m = 0; m < 2; ++m)
#pragma unroll
            for (int r = 0; r < 16; ++r) {
                const float x = acc[m][nf][r] + pv;
                const float e = __expf(2.0f * x);
                const float th = 1.0f - __fdividef(2.0f, e + 1.0f);
                sc2[m][r] = fmaf(vv, th, sc2[m][r]);
            }
    }

    // reduce over the 32-lane column group (offsets < 32 keep h5 fixed)
#pragma unroll
    for (int off = 1; off < 32; off <<= 1)
#pragma unroll
        for (int m = 0; m < 2; ++m)
#pragma unroll
            for (int r = 0; r < 16; ++r)
                sc2[m][r] += __shfl_xor(sc2[m][r], off, 64);

    __syncthreads();   // all LDS A-reads done; reuse as partials buffer
    float* slds = (float*)lds_a;   // [8 waves][64 rows]
    if (l31 == 0) {
#pragma unroll
        for (int m = 0; m < 2; ++m)
#pragma unroll
            for (int r = 0; r < 16; ++r) {
                const int row = m * 32 + (r & 3) + 8 * (r >> 2) + 4 * h5;
                slds[wid * 64 + row] = sc2[m][r];
            }
    }
    __syncthreads();
    if (t < 64) {
        float v = 0.f;
#pragma unroll
        for (int w = 0; w < 8; ++w) v += slds[w * 64 + t];
        scores[m_base + t] = v;
    }
}

// ---- kernel 3: row softmax over S=2048 per batch ----
__global__ void softmax_k(const float* __restrict__ sc, float* __restrict__ out) {
    const int b = blockIdx.x;   // 32
    const int t = threadIdx.x;  // 256
    const int lane = t & 63;
    const int w = t >> 6;
    const float* row = sc + (size_t)b * 2048;
    float x[8];
#pragma unroll
    for (int i = 0; i < 8; ++i) x[i] = row[i * 256 + t];
    float m = x[0];
#pragma unroll
    for (int i = 1; i < 8; ++i) m = fmaxf(m, x[i]);
#pragma unroll
    for (int off = 32; off >= 1; off >>= 1) m = fmaxf(m, __shfl_xor(m, off, 64));
    __shared__ float sred[4];
    __shared__ float sred2[4];
    if (lane == 0) sred[w] = m;
    __syncthreads();
    m = fmaxf(fmaxf(sred[0], sred[1]), fmaxf(sred[2], sred[3]));
    float ssum = 0.f;
#pragma unroll
    for (int i = 0; i < 8; ++i) { x[i] = expf(x[i] - m); ssum += x[i]; }
#pragma unroll
    for (int off = 32; off >= 1; off >>= 1) ssum += __shfl_xor(ssum, off, 64);
    if (lane == 0) sred2[w] = ssum;
    __syncthreads();
    const float inv = 1.0f / (sred2[0] + sred2[1] + sred2[2] + sred2[3]);
#pragma unroll
    for (int i = 0; i < 8; ++i) out[(size_t)b * 2048 + i * 256 + t] = x[i] * inv;
}

extern "C" void kernel_launch(void* const* d_in, const int* in_sizes, int n_in,
                              void* d_out, int out_size, void* d_ws, size_t ws_size,
                              hipStream_t stream) {
    const float* s      = (const float*)d_in[0];
    const float* enc    = (const float*)d_in[1];
    const float* attn_w = (const float*)d_in[2];
    const float* vw     = (const float*)d_in[3];
    float* out = (float*)d_out;

    unsigned short* we = (unsigned short*)d_ws;                             // 2 MB bf16 we_t
    float* ps     = (float*)((char*)d_ws + (2u << 20));                     // 128 KB proj_s
    float* scores = (float*)((char*)d_ws + (2u << 20) + (128u << 10));      // 256 KB scores

    cvt_we_k<<<1024, 256, 0, stream>>>(attn_w, we);
    proj_s_k<<<256, 256, 0, stream>>>(s, attn_w, ps);
    fused_main_k<<<1024, 512, 0, stream>>>(enc, we, ps, vw, scores);
    softmax_k<<<32, 256, 0, stream>>>(scores, out);
}